// Round 3
// baseline (66.888 us; speedup 1.0000x reference)
//
#include <hip/hip_runtime.h>
#include <math.h>

#define NB 128
#define NC 1000
#define NT 800
#define NWAVES 16
#define BLK 1024

// One block per row, 16 waves. K-ary (16-way) monotone search over the
// temperature grid: conf_t(j) is monotone increasing in j, so the reference's
// argmax(ok) equals the first j that is not strictly-below the tolerance band.
// Each wave evaluates one probe temperature independently (wave-local shfl
// reduce, no cross-wave barrier inside an eval); one barrier per round.
// 800 -> <=47 -> <=3 -> resolved: 3 rounds. Per-element math is identical to
// the round-1/2 kernels that passed (IEEE div, precise expf/logf).
__global__ __launch_bounds__(BLK) void logitcomp_kernel(const float* __restrict__ logits,
                                                        float* __restrict__ out) {
    __shared__ float srow[NC];
    __shared__ float sred[NWAVES];
    __shared__ float sconf[NWAVES];
    __shared__ float sbcast;

    int r = blockIdx.x;
    int tid = threadIdx.x;
    int wave = tid >> 6;
    int lane = tid & 63;
    const float* row = logits + r * NC;

    // stage row
    for (int i = tid; i < NC; i += BLK) srow[i] = row[i];
    __syncthreads();

    // row max (exact)
    float mv = (tid < NC) ? srow[tid] : -INFINITY;
    for (int o = 32; o > 0; o >>= 1) mv = fmaxf(mv, __shfl_xor(mv, o, 64));
    if (lane == 0) sred[wave] = mv;
    __syncthreads();
    if (tid == 0) {
        float mm = sred[0];
        for (int w = 1; w < NWAVES; ++w) mm = fmaxf(mm, sred[w]);
        sbcast = mm;
    }
    __syncthreads();
    float m = sbcast;
    __syncthreads();           // sbcast reused below

    // S at t=1 (l/1 == l exactly)
    float s1 = (tid < NC) ? expf(srow[tid] - m) : 0.f;
    for (int o = 32; o > 0; o >>= 1) s1 += __shfl_xor(s1, o, 64);
    if (lane == 0) sred[wave] = s1;
    __syncthreads();
    if (tid == 0) {
        float S = 0.f;
        for (int w = 0; w < NWAVES; ++w) S += sred[w];
        sbcast = S;
    }
    __syncthreads();
    float conf = 1.0f / sbcast;

    // bin + new_conf (uniform)
    const float third = (float)(1.0 / 3.0);
    const float twoth = (float)(2.0 / 3.0);
    bool b0 = (third > conf) && (0.0f <= conf);
    bool b1 = (twoth > conf) && (third <= conf);
    bool b2 = (1.0f > conf) && (twoth <= conf);
    int idx = b0 ? 0 : (b1 ? 1 : (b2 ? 2 : 0));
    float bl = (idx == 0) ? 0.0f : ((idx == 1) ? third : twoth);
    float nb = (idx == 0) ? 0.8f : ((idx == 1) ? (float)0.86666666666 : (float)0.93333333333);
    const float TARGET = (float)0.2666666667;
    const float K = (float)(1.0 / 15.0);
    float nc = nb + K * ((conf - bl) / TARGET);

    // Monotone k-ary search. Invariant: answer (first !below index) is in
    // [lo, hi]; hi is a known !below index with membership flag okhi
    // (hi==NT sentinel: no !below index found yet -> found=false).
    int lo = 0, hi = NT;
    bool okhi = false;

    while (lo < hi) {
        int count = hi - lo;
        int np = (count <= NWAVES) ? count : NWAVES;

        if (wave < np) {
            int p = (count <= NWAVES) ? (lo + wave)
                                      : (lo + ((wave + 1) * count) / 17);
            float t = 1.0f - 0.00125f * (float)p;    // temps[p] in f32
            float m2 = m / t;                        // == max(scaled) (monotone rounding)
            float sw = 0.f;
            for (int i = lane; i < NC; i += 64)
                sw += expf(srow[i] / t - m2);        // IEEE div, precise expf
            for (int o = 32; o > 0; o >>= 1) sw += __shfl_xor(sw, o, 64);
            if (lane == 0) {
                float lse = m2 + logf(sw);
                sconf[wave] = expf(m2 - lse);        // conf_t, reference expression
            }
        }
        __syncthreads();

        // uniform narrowing (every thread redundantly, identical result)
        int firsti = -1;
        float cfound = 0.f;
        for (int i = 0; i < np; ++i) {
            float c = sconf[i];
            bool oki = fabsf(c - nc) <= 0.01f;       // reference membership predicate
            bool below = (c < nc) && !oki;
            if (!below) { firsti = i; cfound = c; break; }
        }
        __syncthreads();                              // sconf safe to rewrite next round

        if (count <= NWAVES) {
            if (firsti >= 0) { hi = lo + firsti; okhi = fabsf(cfound - nc) <= 0.01f; }
            lo = hi;                                  // fully resolved
        } else {
            if (firsti < 0) {
                lo = lo + (NWAVES * count) / 17 + 1;  // past last probe
            } else {
                int pf = lo + ((firsti + 1) * count) / 17;
                int nl = (firsti > 0) ? (lo + (firsti * count) / 17 + 1) : lo;
                hi = pf;
                okhi = fabsf(cfound - nc) <= 0.01f;
                lo = nl;
            }
        }
    }

    bool found = okhi && (hi < NT);
    float tch = 1.0f - 0.00125f * (float)hi;

    // write output (IEEE divide matches logits/chosen_temp)
    float* orow = out + r * NC;
    for (int i = tid; i < NC; i += BLK) {
        float l = srow[i];
        orow[i] = found ? (l / tch) : l;
    }
}

extern "C" void kernel_launch(void* const* d_in, const int* in_sizes, int n_in,
                              void* d_out, int out_size, void* d_ws, size_t ws_size,
                              hipStream_t stream) {
    const float* logits = (const float*)d_in[0];
    float* out = (float*)d_out;
    logitcomp_kernel<<<NB, BLK, 0, stream>>>(logits, out);
}